// Round 1
// baseline (237.573 us; speedup 1.0000x reference)
//
#include <hip/hip_runtime.h>
#include <hip/hip_bf16.h>
#include <stdint.h>

#define GAT_ALPHA 0.2f
#define LOG2E 1.4426950408889634f

typedef __attribute__((ext_vector_type(8))) __bf16 bf16x8;
typedef __attribute__((ext_vector_type(4))) float f32x4;

union B8 {
  bf16x8 b;
  unsigned short u[8];
  unsigned int w[4];
  int4 i4;
};

// packed fp32x2 -> bf16x2 RNE (v_cvt_pk_bf16_f32 on gfx950)
__device__ __forceinline__ unsigned int pk2bf(float lo, float hi) {
  union { __hip_bfloat162 h; unsigned int u; } cv;
  cv.h = __float22bfloat162_rn(make_float2(lo, hi));
  return cv.u;
}

// async global->LDS DMA, 16B per lane: dest = lds_base + lane*16 (wave-uniform base)
__device__ __forceinline__ void dma16(const void* g, void* l) {
  __builtin_amdgcn_global_load_lds(
      (const __attribute__((address_space(1))) unsigned int*)g,
      (__attribute__((address_space(3))) unsigned int*)l, 16, 0, 0);
}

// ---------------- Kernel A: wh = x @ W^T via bf16 MFMA (fp32 accumulate) -----------
// 256 blocks x 256 thr (4 waves); block = 64 rows x 128 o. Wave w: rows 16w..16w+15.
// A-frags (x) loaded from global fp32 + cvt_pk (each byte read once). W staged in LDS
// as bf16 frags, two 32 KB k-halves. s,d from fp32 accumulators; whTf in frag order.
__global__ __launch_bounds__(256, 2) void gat_wh(
    const float* __restrict__ x, const float* __restrict__ W,
    const float* __restrict__ a, unsigned short* __restrict__ whTf,
    float* __restrict__ s_out, float* __restrict__ d_out) {
  __shared__ unsigned short WF[8][4][512];   // 32 KB: [nt][kc_local][frag shorts]
  const int tid = threadIdx.x;
  const int wave = tid >> 6, lane = tid & 63;
  const int il = lane & 15, quad = lane >> 4;
  const int row0 = blockIdx.x * 64;
  const int i = row0 + wave * 16 + il;
  B8 av[8];
  {
    const float* xp = x + (size_t)i * 256 + quad * 8;
#pragma unroll
    for (int kc = 0; kc < 8; ++kc) {
      float4 lo = *(const float4*)(xp + kc * 32);
      float4 hi = *(const float4*)(xp + kc * 32 + 4);
      av[kc].w[0] = pk2bf(lo.x, lo.y);
      av[kc].w[1] = pk2bf(lo.z, lo.w);
      av[kc].w[2] = pk2bf(hi.x, hi.y);
      av[kc].w[3] = pk2bf(hi.z, hi.w);
    }
  }
  f32x4 acc[8];
#pragma unroll
  for (int nt = 0; nt < 8; ++nt) acc[nt] = (f32x4){0.f, 0.f, 0.f, 0.f};
#pragma unroll
  for (int h = 0; h < 2; ++h) {
    if (h) __syncthreads();
#pragma unroll
    for (int p = 0; p < 16; ++p) {
      const int f = p * 1024 + tid * 4;
      const int o = f >> 7, kk = f & 127;
      float4 v = *(const float4*)(W + o * 256 + h * 128 + kk);
      uint2 pk;
      pk.x = pk2bf(v.x, v.y);
      pk.y = pk2bf(v.z, v.w);
      *(uint2*)(&WF[o >> 4][kk >> 5][((o & 15) + (((kk & 31) >> 3) << 4)) * 8 + (kk & 7)]) = pk;
    }
    __syncthreads();
#pragma unroll
    for (int kl = 0; kl < 4; ++kl) {
      const int kc = h * 4 + kl;
#pragma unroll
      for (int nt = 0; nt < 8; ++nt) {
        B8 bv;
        bv.i4 = *(const int4*)(&WF[nt][kl][lane * 8]);
        acc[nt] = __builtin_amdgcn_mfma_f32_16x16x32_bf16(av[kc].b, bv.b, acc[nt], 0, 0, 0);
      }
    }
  }
  float asrc[8], adst[8];
#pragma unroll
  for (int nt = 0; nt < 8; ++nt) {
    asrc[nt] = a[nt * 16 + il];
    adst[nt] = a[128 + nt * 16 + il];
  }
  float sp[4], dp[4];
#pragma unroll
  for (int r = 0; r < 4; ++r) {
    float sv = 0.f, dv = 0.f;
#pragma unroll
    for (int nt = 0; nt < 8; ++nt) {
      sv += acc[nt][r] * asrc[nt];
      dv += acc[nt][r] * adst[nt];
    }
    sp[r] = sv; dp[r] = dv;
  }
#pragma unroll
  for (int off = 1; off <= 8; off <<= 1) {
#pragma unroll
    for (int r = 0; r < 4; ++r) {
      sp[r] += __shfl_xor(sp[r], off, 64);
      dp[r] += __shfl_xor(dp[r], off, 64);
    }
  }
  if (il == 0) {
#pragma unroll
    for (int r = 0; r < 4; ++r) {
      s_out[row0 + wave * 16 + quad * 4 + r] = sp[r];
      d_out[row0 + wave * 16 + quad * 4 + r] = dp[r];
    }
  }
  const int b = row0 >> 11;
  const int jc = ((row0 & 2047) >> 5) + (wave >> 1);
  const int kin = ((wave & 1) << 4) + (quad << 2);
  const int kq = kin >> 3, u0 = kin & 7;
#pragma unroll
  for (int nt = 0; nt < 8; ++nt) {
    uint2 pk;
    pk.x = pk2bf(acc[nt][0], acc[nt][1]);
    pk.y = pk2bf(acc[nt][2], acc[nt][3]);
    *(uint2*)(whTf + ((((size_t)(b * 64 + jc)) * 8 + nt) << 9) + ((il + (kq << 4)) << 3) + u0) = pk;
  }
}

// ---------------- Kernel B: fused mask+attention, counted-vmcnt pipelined MFMA -----
// 256 blocks (1/CU); b = blk&7 pins batch to one XCD (whTf L2-resident). Per T:
// issue V-DMAs for T+1 FIRST, then adj loads for pair T+2 (2-deep, lvA/lvB double
// buffer). End-of-iteration barrier is raw s_barrier + s_waitcnt vmcnt(16): the 4
// DMAs (oldest) drain, the 16 adj loads STAY IN FLIGHT across the barrier and get
// ~1.5 iterations to land (vs the old __syncthreads vmcnt(0) drain which serialized
// full HBM latency into every one of the 32 iterations at 1 wave/SIMD occupancy).
#define ATTN_COMPUTE(Tval, CUR)                                                    \
  _Pragma("unroll") for (int c = 0; c < 2; ++c) {                                  \
    const int j0 = (2 * (Tval) + c) * 32;                                          \
    const unsigned int mq = (unsigned int)(mcur >> (32 * c + qo));                 \
    const float4 d0 = *(const float4*)(&dl[j0 + qo]);                              \
    const float4 d1 = *(const float4*)(&dl[j0 + qo + 4]);                          \
    const float dd[8] = {d0.x, d0.y, d0.z, d0.w, d1.x, d1.y, d1.z, d1.w};          \
    B8 af[8];                                                                      \
    _Pragma("unroll") for (int nt = 0; nt < 8; ++nt)                               \
        af[nt].i4 = *(const int4*)((const char*)&vbuf[CUR][c][nt][0] + lane * 16); \
    float pv[8];                                                                   \
    _Pragma("unroll") for (int u = 0; u < 8; ++u) {                                \
      float t0 = svL + dd[u];                                                      \
      float e2 = fmaxf(t0, GAT_ALPHA * t0);                                        \
      float p = __builtin_amdgcn_exp2f(e2);                                        \
      p = ((mq >> u) & 1u) ? p : 0.f;                                              \
      den += p;                                                                    \
      pv[u] = p;                                                                   \
    }                                                                              \
    B8 pf;                                                                         \
    pf.w[0] = pk2bf(pv[0], pv[1]);                                                 \
    pf.w[1] = pk2bf(pv[2], pv[3]);                                                 \
    pf.w[2] = pk2bf(pv[4], pv[5]);                                                 \
    pf.w[3] = pk2bf(pv[6], pv[7]);                                                 \
    _Pragma("unroll") for (int nt = 0; nt < 8; ++nt)                               \
      acc[nt] = __builtin_amdgcn_mfma_f32_16x16x32_bf16(af[nt].b, pf.b,            \
                                                        acc[nt], 0, 0, 0);         \
  }

#define ATTN_BALLOT(LVC)                                                           \
  {                                                                                \
    unsigned long long sel = __ballot(LVC[0] != 0);                                \
    _Pragma("unroll") for (int r = 1; r < 16; ++r) {                               \
      const unsigned long long mm = __ballot(LVC[r] != 0);                         \
      sel = (il == r) ? mm : sel;                                                  \
    }                                                                              \
    mcur = sel;                                                                    \
  }

#define ATTN_DMA(PAIR, NXT)                                                        \
  _Pragma("unroll") for (int h = 0; h < 2; ++h) {                                  \
    const int nt = wave * 2 + h;                                                   \
    dma16(whTb + (((size_t)(2 * (PAIR)) * 8 + nt) << 9) + (lane << 3),             \
          &vbuf[NXT][0][nt][0]);                                                   \
    dma16(whTb + (((size_t)(2 * (PAIR) + 1) * 8 + nt) << 9) + (lane << 3),         \
          &vbuf[NXT][1][nt][0]);                                                   \
  }

__global__ __launch_bounds__(256) void gat_attn(
    const int* __restrict__ adj, const unsigned short* __restrict__ whTf,
    const float* __restrict__ s, const float* __restrict__ dvec,
    float* __restrict__ out) {
  __shared__ unsigned short vbuf[2][2][8][512];  // 32 KB: [buf][chunk][nt][frag]
  __shared__ float dl[2048];                     // 8 KB (pre-scaled by LOG2E)
  const int tid = threadIdx.x;
  const int wave = tid >> 6;
  const int lane = tid & 63;
  const int il = lane & 15;
  const int quad = lane >> 4;
  const int qo = quad << 3;
  const int b = blockIdx.x & 7;
  const int tile = blockIdx.x >> 3;
  const int rbase = tile * 64;
  {
    const float* dsrc = dvec + ((size_t)b << 11);
#pragma unroll
    for (int it = 0; it < 2; ++it) {
      const int idx = it * 1024 + tid * 4;
      float4 v = *(const float4*)(dsrc + idx);
      v.x *= LOG2E; v.y *= LOG2E; v.z *= LOG2E; v.w *= LOG2E;
      *(float4*)(&dl[idx]) = v;
    }
  }
  // adj base for this wave's 16 rows (each row 8 KB apart; loads are 256B coalesced)
  const int* aro = adj + ((((size_t)b << 11) + rbase + wave * 16) << 11);
  int lv0[16], lvA[16], lvB[16];
#pragma unroll
  for (int r = 0; r < 16; ++r) lv0[r] = aro[(r << 11) + lane];         // pair 0
#pragma unroll
  for (int r = 0; r < 16; ++r) lvA[r] = aro[(r << 11) + 64 + lane];    // pair 1
  const unsigned short* whTb = whTf + (((size_t)b * 64) << 12);
  ATTN_DMA(0, 0);  // chunks 0,1 -> vbuf[0]
  const int i = rbase + wave * 16 + il;
  const size_t browi = ((size_t)b << 11) + i;
  const float svL = s[browi] * LOG2E;
  f32x4 acc[8];
#pragma unroll
  for (int nt = 0; nt < 8; ++nt) acc[nt] = (f32x4){0.f, 0.f, 0.f, 0.f};
  float den = 0.f;
  unsigned long long mcur;
  ATTN_BALLOT(lv0);   // mask for pair 0
  __syncthreads();    // drains prologue DMA + dl stores (full drain, once)

  for (int t2 = 0; t2 < 15; ++t2) {
    const int T0 = 2 * t2;
    // ---- T even (cur=0): DMA pair T0+1 -> vbuf[1]; prefetch adj pair T0+2 -> lvB
    {
      ATTN_DMA(T0 + 1, 1);
      __builtin_amdgcn_sched_barrier(0);   // DMAs stay oldest (vmcnt order)
#pragma unroll
      for (int r = 0; r < 16; ++r) lvB[r] = aro[(r << 11) + (T0 + 2) * 64 + lane];
      ATTN_COMPUTE(T0, 0);
      ATTN_BALLOT(lvA);                    // mask for pair T0+1 (loaded 2 iters ago)
      // drain the 4 DMAs only; 16 adj loads remain in flight across the barrier
      asm volatile("s_waitcnt vmcnt(16)\n\ts_barrier" ::: "memory");
    }
    // ---- T odd (cur=1): DMA pair T0+2 -> vbuf[0]; prefetch adj pair T0+3 -> lvA
    {
      const int T1 = T0 + 1;
      ATTN_DMA(T1 + 1, 0);
      __builtin_amdgcn_sched_barrier(0);
#pragma unroll
      for (int r = 0; r < 16; ++r) lvA[r] = aro[(r << 11) + (T1 + 2) * 64 + lane];
      ATTN_COMPUTE(T1, 1);
      ATTN_BALLOT(lvB);
      asm volatile("s_waitcnt vmcnt(16)\n\ts_barrier" ::: "memory");
    }
  }
  // ---- T=30 (cur=0): DMA pair 31 -> vbuf[1]; no more adj prefetch
  {
    ATTN_DMA(31, 1);
    ATTN_COMPUTE(30, 0);
    ATTN_BALLOT(lvA);                      // mask for pair 31
    asm volatile("s_waitcnt vmcnt(0)\n\ts_barrier" ::: "memory");
  }
  // ---- T=31 (cur=1)
  ATTN_COMPUTE(31, 1);

  den += __shfl_xor(den, 16, 64);
  den += __shfl_xor(den, 32, 64);
  const float inv = 1.0f / den;
  float* op = out + browi * 128;
#pragma unroll
  for (int nt = 0; nt < 8; ++nt) {
    float4 v;
    v.x = fmaxf(acc[nt][0] * inv, 0.f);
    v.y = fmaxf(acc[nt][1] * inv, 0.f);
    v.z = fmaxf(acc[nt][2] * inv, 0.f);
    v.w = fmaxf(acc[nt][3] * inv, 0.f);
    *(float4*)(op + nt * 16 + quad * 4) = v;
  }
}

extern "C" void kernel_launch(void* const* d_in, const int* in_sizes, int n_in,
                              void* d_out, int out_size, void* d_ws, size_t ws_size,
                              hipStream_t stream) {
  const float* x = (const float*)d_in[0];
  const int* adj = (const int*)d_in[1];
  const float* W = (const float*)d_in[2];
  const float* a = (const float*)d_in[3];
  float* out = (float*)d_out;
  // ws: whTf bf16 4 MB | s fp32 64 KB | d fp32 64 KB
  unsigned short* whTf = (unsigned short*)d_ws;
  float* s = (float*)((char*)d_ws + (size_t)4 * 1024 * 1024);
  float* dv = s + 16384;
  gat_wh<<<256, 256, 0, stream>>>(x, W, a, whTf, s, dv);
  gat_attn<<<256, 256, 0, stream>>>(adj, whTf, s, dv, out);
}